// Round 9
// baseline (212.604 us; speedup 1.0000x reference)
//
#include <hip/hip_runtime.h>
#include <stdint.h>
#include <stddef.h>

#define IN_F   1024
#define OUT_F  1024
#define NROWS  16384
#define NTERMS 10

#define CAST_BLOCKS ((NROWS * IN_F) / (256 * 8))   // 8192
#define PREP_BLOCKS ((OUT_F * IN_F) / 256)         // 4096

typedef __bf16 bf16x8 __attribute__((ext_vector_type(8)));
typedef float  f32x4  __attribute__((ext_vector_type(4)));
typedef unsigned short u16x8 __attribute__((ext_vector_type(8)));

union V8 { u16x8 u; bf16x8 b; };

__device__ __forceinline__ unsigned short f2bf(float f) {
    unsigned int u = __float_as_uint(f);
    unsigned int r = (u + 0x7FFFu + ((u >> 16) & 1u)) >> 16;
    return (unsigned short)r;
}

// ---------------------------------------------------- fused prep: cast x + weights
__global__ __launch_bounds__(256)
void prep_all_kernel(const float* __restrict__ x, unsigned short* __restrict__ xb,
                     const float* __restrict__ bw, const float* __restrict__ sw,
                     unsigned short* __restrict__ wb, unsigned short* __restrict__ wm) {
    __shared__ float s[256 * NTERMS];
    const int tid = threadIdx.x;

    if (blockIdx.x < CAST_BLOCKS) {
        size_t i = ((size_t)blockIdx.x * 256 + tid) * 8;
        float4 a = *(const float4*)(x + i);
        float4 b = *(const float4*)(x + i + 4);
        u16x8 o;
        o[0] = f2bf(a.x); o[1] = f2bf(a.y); o[2] = f2bf(a.z); o[3] = f2bf(a.w);
        o[4] = f2bf(b.x); o[5] = f2bf(b.y); o[6] = f2bf(b.z); o[7] = f2bf(b.w);
        *(u16x8*)(xb + i) = o;
    } else {
        const size_t base = (size_t)(blockIdx.x - CAST_BLOCKS) * 256;
        const float4* src = (const float4*)(sw + base * NTERMS);
#pragma unroll
        for (int it = 0; it < 3; ++it) {
            int j = tid + it * 256;
            if (j < (256 * NTERMS) / 4) ((float4*)s)[j] = src[j];
        }
        __syncthreads();
        float sum = 0.f;
#pragma unroll
        for (int t = 0; t < NTERMS; ++t) sum += s[tid * NTERMS + t];
        size_t i = base + tid;
        wm[i] = f2bf(sum * 0.1f);
        wb[i] = f2bf(bw[i]);
    }
}

// ---------------------------------------------------------------- fused dual GEMM
// out[m][n] = silu( sum_k x[m][k]*Wb[n][k] ) + sum_k x[m][k]*Wm[n][k]
// 2-barrier m97 K-loop (proven best), BK=64, XOR bank swizzle, 128x128 tile.
//
// ROUND-9 CHANGE (occupancy): 512 threads = 8 waves (2M x 4N); each wave owns
// 64x32 x {base,spline}. Accumulator shrinks 128 -> 64 AGPR/wave, total regs
// target <=128 (__launch_bounds__(512,4)) to cross the m69 occupancy cliff:
// 8 waves/CU -> 16 waves/CU (4/SIMD, 2 independent barrier domains/SIMD-pair).
// Attacks the 35 µs stall gap (MFMA floor 33 µs vs 68 µs measured) that no
// schedule variant could amortize at 2 waves/SIMD. Cost: A frags read by 4
// waves instead of 2 (+33% LDS b128 traffic ~ +3 µs at 256 B/cyc/CU).
// Numerics identical (same MFMA shape, same ascending-k accumulation).
//
// Session ledger (do not re-try): 8-phase counted-vmcnt x3 (73/84/78 µs),
// 32x32x16 shape (84 µs, 6.3M conflicts), Wm global->reg (106 µs),
// NT stores (81.5 µs, WRITE +43%). R6/R8 4-wave structure = 68 µs baseline.
__global__ __launch_bounds__(512, 4)
void kan_gemm(const unsigned short* __restrict__ xb,
              const unsigned short* __restrict__ wbq,
              const unsigned short* __restrict__ wmq,
              float* __restrict__ out) {
    __shared__ __align__(16) unsigned short As[128 * 64];
    __shared__ __align__(16) unsigned short Bs[2][128 * 64];

    const int tid  = threadIdx.x;
    const int lane = tid & 63;
    const int wave = tid >> 6;       // 0..7
    const int wm_  = wave >> 2;      // 0..1 : M half (64 rows)
    const int wn_  = wave & 3;       // 0..3 : N quarter (32 cols)
    const int rowl = lane & 15;
    const int quad = lane >> 4;

    const int m0 = blockIdx.x * 128;
    const int n0 = blockIdx.y * 128;

    f32x4 acc[2][4][2];              // [s][mt][nt] -> 64 AGPR
#pragma unroll
    for (int s = 0; s < 2; ++s)
#pragma unroll
        for (int mt = 0; mt < 4; ++mt)
#pragma unroll
            for (int nt = 0; nt < 2; ++nt)
                acc[s][mt][nt] = (f32x4){0.f, 0.f, 0.f, 0.f};

    // staging: 1024 chunks (16 B) per 128x64 tile, 2 per thread per tile
    int srow[2], sgc[2];             // row, swizzled global chunk
#pragma unroll
    for (int j = 0; j < 2; ++j) {
        int q = tid + j * 512;
        int r = q >> 3, cd = q & 7;
        srow[j] = r;
        sgc[j] = cd ^ (r & 7);
    }

    for (int k0 = 0; k0 < IN_F; k0 += 64) {
        __syncthreads();
#pragma unroll
        for (int j = 0; j < 2; ++j) {
            int q = tid + j * 512;
            const unsigned short* ga = xb + (size_t)(m0 + srow[j]) * IN_F + k0 + sgc[j] * 8;
            __builtin_amdgcn_global_load_lds(
                (const __attribute__((address_space(1))) unsigned int*)ga,
                (__attribute__((address_space(3))) unsigned int*)(As + q * 8), 16, 0, 0);
            const unsigned short* gb = wbq + (size_t)(n0 + srow[j]) * IN_F + k0 + sgc[j] * 8;
            __builtin_amdgcn_global_load_lds(
                (const __attribute__((address_space(1))) unsigned int*)gb,
                (__attribute__((address_space(3))) unsigned int*)(Bs[0] + q * 8), 16, 0, 0);
            const unsigned short* gm = wmq + (size_t)(n0 + srow[j]) * IN_F + k0 + sgc[j] * 8;
            __builtin_amdgcn_global_load_lds(
                (const __attribute__((address_space(1))) unsigned int*)gm,
                (__attribute__((address_space(3))) unsigned int*)(Bs[1] + q * 8), 16, 0, 0);
        }
        __syncthreads();

#pragma unroll
        for (int ksub = 0; ksub < 2; ++ksub) {
            bf16x8 afrag[4], bfrag[2][2];
#pragma unroll
            for (int mt = 0; mt < 4; ++mt) {
                int r = wm_ * 64 + mt * 16 + rowl;
                int c = (ksub * 4 + quad) ^ (r & 7);
                union V8 t;
                t.u = *(const u16x8*)(As + r * 64 + c * 8);
                afrag[mt] = t.b;
            }
#pragma unroll
            for (int s = 0; s < 2; ++s)
#pragma unroll
                for (int nt = 0; nt < 2; ++nt) {
                    int r = wn_ * 32 + nt * 16 + rowl;
                    int c = (ksub * 4 + quad) ^ (r & 7);
                    union V8 t;
                    t.u = *(const u16x8*)(Bs[s] + r * 64 + c * 8);
                    bfrag[s][nt] = t.b;
                }
#pragma unroll
            for (int s = 0; s < 2; ++s)
#pragma unroll
                for (int mt = 0; mt < 4; ++mt)
#pragma unroll
                    for (int nt = 0; nt < 2; ++nt)
                        acc[s][mt][nt] = __builtin_amdgcn_mfma_f32_16x16x32_bf16(
                            afrag[mt], bfrag[s][nt], acc[s][mt][nt], 0, 0, 0);
        }
    }

    // epilogue: silu(base) + spline, fp32 store (plain stores: NT stores
    // measured +43% WRITE_SIZE). C/D layout: col = lane&15, row = quad*4 + reg
#pragma unroll
    for (int mt = 0; mt < 4; ++mt)
#pragma unroll
        for (int nt = 0; nt < 2; ++nt)
#pragma unroll
            for (int r = 0; r < 4; ++r) {
                float vb = acc[0][mt][nt][r];
                float vm = acc[1][mt][nt][r];
                float o  = vb / (1.0f + __expf(-vb)) + vm;
                int row = m0 + wm_ * 64 + mt * 16 + quad * 4 + r;
                int col = n0 + wn_ * 32 + nt * 16 + rowl;
                out[(size_t)row * OUT_F + col] = o;
            }
}

extern "C" void kernel_launch(void* const* d_in, const int* in_sizes, int n_in,
                              void* d_out, int out_size, void* d_ws, size_t ws_size,
                              hipStream_t stream) {
    const float* x  = (const float*)d_in[0];   // [16384,1024]
    const float* bw = (const float*)d_in[1];   // [1024,1024]
    const float* sw = (const float*)d_in[2];   // [1024,1024,10]
    float* out = (float*)d_out;                // [16384,1024]

    unsigned short* xb  = (unsigned short*)d_ws;
    unsigned short* wbq = xb + (size_t)NROWS * IN_F;
    unsigned short* wmq = wbq + (size_t)OUT_F * IN_F;

    prep_all_kernel<<<dim3(CAST_BLOCKS + PREP_BLOCKS), dim3(256), 0, stream>>>(
        x, xb, bw, sw, wbq, wmq);
    kan_gemm<<<dim3(NROWS / 128, OUT_F / 128), dim3(512), 0, stream>>>(xb, wbq, wmq, out);
}

// Round 10
// 209.082 us; speedup vs baseline: 1.0168x; 1.0168x over previous
//
#include <hip/hip_runtime.h>
#include <stdint.h>
#include <stddef.h>

#define IN_F   1024
#define OUT_F  1024
#define NROWS  16384
#define NTERMS 10

#define CAST_BLOCKS ((NROWS * IN_F) / (256 * 8))   // 8192
#define PREP_BLOCKS ((OUT_F * IN_F) / 256)         // 4096

typedef __bf16 bf16x8 __attribute__((ext_vector_type(8)));
typedef float  f32x4  __attribute__((ext_vector_type(4)));
typedef unsigned short u16x8 __attribute__((ext_vector_type(8)));

union V8 { u16x8 u; bf16x8 b; };

__device__ __forceinline__ unsigned short f2bf(float f) {
    unsigned int u = __float_as_uint(f);
    unsigned int r = (u + 0x7FFFu + ((u >> 16) & 1u)) >> 16;
    return (unsigned short)r;
}

// ---------------------------------------------------- fused prep: cast x + weights
// blocks [0, CAST_BLOCKS)            : x fp32 -> bf16 (8 elems/thread)
// blocks [CAST_BLOCKS, +PREP_BLOCKS) : base W -> bf16 ; mean spline W -> bf16
__global__ __launch_bounds__(256)
void prep_all_kernel(const float* __restrict__ x, unsigned short* __restrict__ xb,
                     const float* __restrict__ bw, const float* __restrict__ sw,
                     unsigned short* __restrict__ wb, unsigned short* __restrict__ wm) {
    __shared__ float s[256 * NTERMS];
    const int tid = threadIdx.x;

    if (blockIdx.x < CAST_BLOCKS) {
        size_t i = ((size_t)blockIdx.x * 256 + tid) * 8;
        float4 a = *(const float4*)(x + i);
        float4 b = *(const float4*)(x + i + 4);
        u16x8 o;
        o[0] = f2bf(a.x); o[1] = f2bf(a.y); o[2] = f2bf(a.z); o[3] = f2bf(a.w);
        o[4] = f2bf(b.x); o[5] = f2bf(b.y); o[6] = f2bf(b.z); o[7] = f2bf(b.w);
        *(u16x8*)(xb + i) = o;
    } else {
        const size_t base = (size_t)(blockIdx.x - CAST_BLOCKS) * 256;
        const float4* src = (const float4*)(sw + base * NTERMS);
#pragma unroll
        for (int it = 0; it < 3; ++it) {
            int j = tid + it * 256;
            if (j < (256 * NTERMS) / 4) ((float4*)s)[j] = src[j];
        }
        __syncthreads();
        float sum = 0.f;
#pragma unroll
        for (int t = 0; t < NTERMS; ++t) sum += s[tid * NTERMS + t];
        size_t i = base + tid;
        wm[i] = f2bf(sum * 0.1f);
        wb[i] = f2bf(bw[i]);
    }
}

// ---------------------------------------------------------------- fused dual GEMM
// out[m][n] = silu( sum_k x[m][k]*Wb[n][k] ) + sum_k x[m][k]*Wm[n][k]
// 2-barrier m97 K-loop, BK=64, XOR bank swizzle, 128x128 tile, 4 waves.
// PROVEN BEST (R6/R8): 67.2-68.2 µs GEMM, MfmaUtil ~42-44%, FETCH 49.2 MB,
// WRITE 65.5 MB, bank conflicts 0. This restore is the session's final kernel.
//
// Session ledger — every axis falsified with counter evidence, do not re-try:
//   8-phase counted-vmcnt x3 variants -> 73/84/78 µs (no overlap at 128² tile;
//       deeper prefetch monotonically worse)
//   32x32x16 shape + extended swizzle -> 84 µs (6.3M bank conflicts)
//   Wm global->reg                    -> 106 µs (L2 latency on critical path)
//   non-temporal output stores        -> 81.5 µs (WRITE +43%, no write-coalesce;
//       FETCH unchanged => no L2-pollution benefit existed)
//   8-wave occupancy split            -> 90 µs (VGPR 60, occupancy 31% — but
//       per-wave MFMA/barrier halved, +50% redundant A-frag LDS reads;
//       LDS-read pipe, not TLP, is the binding constraint)
//
// Ceiling statement: MFMA floor 33 µs; measured 68 µs. The structure is
// balanced (LDS-read ~ MFMA ~ 40% each, staging drain the rest; no pipe >50%).
// Breaking 68 µs requires fp8/MX inputs (changes numerics vs fp32 reference)
// or hand-asm K-loop interleave beyond plain-HIP scheduling control.
__global__ __launch_bounds__(256, 2)
void kan_gemm(const unsigned short* __restrict__ xb,
              const unsigned short* __restrict__ wbq,
              const unsigned short* __restrict__ wmq,
              float* __restrict__ out) {
    __shared__ __align__(16) unsigned short As[128 * 64];
    __shared__ __align__(16) unsigned short Bs[2][128 * 64];

    const int tid  = threadIdx.x;
    const int lane = tid & 63;
    const int wave = tid >> 6;
    const int wm_  = wave >> 1;      // m half
    const int wn_  = wave & 1;       // n half
    const int rowl = lane & 15;
    const int quad = lane >> 4;

    const int m0 = blockIdx.x * 128;
    const int n0 = blockIdx.y * 128;

    f32x4 acc[2][4][4];
#pragma unroll
    for (int s = 0; s < 2; ++s)
#pragma unroll
        for (int mt = 0; mt < 4; ++mt)
#pragma unroll
            for (int nt = 0; nt < 4; ++nt)
                acc[s][mt][nt] = (f32x4){0.f, 0.f, 0.f, 0.f};

    // staging: 1024 chunks (16 B) per 128x64 tile, 4 per thread per tile
    int srow[4], sgc[4];   // row, swizzled global chunk (same for all 3 tiles)
#pragma unroll
    for (int j = 0; j < 4; ++j) {
        int q = tid + j * 256;
        int r = q >> 3, cd = q & 7;
        srow[j] = r;
        sgc[j] = cd ^ (r & 7);
    }

    for (int k0 = 0; k0 < IN_F; k0 += 64) {
        __syncthreads();
#pragma unroll
        for (int j = 0; j < 4; ++j) {
            int q = tid + j * 256;
            const unsigned short* ga = xb + (size_t)(m0 + srow[j]) * IN_F + k0 + sgc[j] * 8;
            __builtin_amdgcn_global_load_lds(
                (const __attribute__((address_space(1))) unsigned int*)ga,
                (__attribute__((address_space(3))) unsigned int*)(As + q * 8), 16, 0, 0);
            const unsigned short* gb = wbq + (size_t)(n0 + srow[j]) * IN_F + k0 + sgc[j] * 8;
            __builtin_amdgcn_global_load_lds(
                (const __attribute__((address_space(1))) unsigned int*)gb,
                (__attribute__((address_space(3))) unsigned int*)(Bs[0] + q * 8), 16, 0, 0);
            const unsigned short* gm = wmq + (size_t)(n0 + srow[j]) * IN_F + k0 + sgc[j] * 8;
            __builtin_amdgcn_global_load_lds(
                (const __attribute__((address_space(1))) unsigned int*)gm,
                (__attribute__((address_space(3))) unsigned int*)(Bs[1] + q * 8), 16, 0, 0);
        }
        __syncthreads();

#pragma unroll
        for (int ksub = 0; ksub < 2; ++ksub) {
            bf16x8 afrag[4], bfrag[2][4];
#pragma unroll
            for (int mt = 0; mt < 4; ++mt) {
                int r = wm_ * 64 + mt * 16 + rowl;
                int c = (ksub * 4 + quad) ^ (r & 7);
                union V8 t;
                t.u = *(const u16x8*)(As + r * 64 + c * 8);
                afrag[mt] = t.b;
            }
#pragma unroll
            for (int s = 0; s < 2; ++s)
#pragma unroll
                for (int nt = 0; nt < 4; ++nt) {
                    int r = wn_ * 64 + nt * 16 + rowl;
                    int c = (ksub * 4 + quad) ^ (r & 7);
                    union V8 t;
                    t.u = *(const u16x8*)(Bs[s] + r * 64 + c * 8);
                    bfrag[s][nt] = t.b;
                }
#pragma unroll
            for (int s = 0; s < 2; ++s)
#pragma unroll
                for (int mt = 0; mt < 4; ++mt)
#pragma unroll
                    for (int nt = 0; nt < 4; ++nt)
                        acc[s][mt][nt] = __builtin_amdgcn_mfma_f32_16x16x32_bf16(
                            afrag[mt], bfrag[s][nt], acc[s][mt][nt], 0, 0, 0);
        }
    }

    // epilogue: silu(base) + spline, fp32 store (plain stores: NT stores
    // measured +43% WRITE_SIZE). C/D layout: col = lane&15, row = quad*4 + reg
#pragma unroll
    for (int mt = 0; mt < 4; ++mt)
#pragma unroll
        for (int nt = 0; nt < 4; ++nt)
#pragma unroll
            for (int r = 0; r < 4; ++r) {
                float vb = acc[0][mt][nt][r];
                float vm = acc[1][mt][nt][r];
                float o  = vb / (1.0f + __expf(-vb)) + vm;
                int row = m0 + wm_ * 64 + mt * 16 + quad * 4 + r;
                int col = n0 + wn_ * 64 + nt * 16 + rowl;
                out[(size_t)row * OUT_F + col] = o;
            }
}

extern "C" void kernel_launch(void* const* d_in, const int* in_sizes, int n_in,
                              void* d_out, int out_size, void* d_ws, size_t ws_size,
                              hipStream_t stream) {
    const float* x  = (const float*)d_in[0];   // [16384,1024]
    const float* bw = (const float*)d_in[1];   // [1024,1024]
    const float* sw = (const float*)d_in[2];   // [1024,1024,10]
    float* out = (float*)d_out;                // [16384,1024]

    unsigned short* xb  = (unsigned short*)d_ws;
    unsigned short* wbq = xb + (size_t)NROWS * IN_F;
    unsigned short* wmq = wbq + (size_t)OUT_F * IN_F;

    prep_all_kernel<<<dim3(CAST_BLOCKS + PREP_BLOCKS), dim3(256), 0, stream>>>(
        x, xb, bw, sw, wbq, wmq);
    kan_gemm<<<dim3(NROWS / 128, OUT_F / 128), dim3(256), 0, stream>>>(xb, wbq, wmq, out);
}